// Round 4
// baseline (127.259 us; speedup 1.0000x reference)
//
#include <hip/hip_runtime.h>
#include <math.h>

// Problem constants
#define BATCH 2
#define NTOK  2048
#define FIN   256
#define HEADS 8
#define FOUT  32
#define BH    (BATCH*HEADS)    // 16
#define NCOL  (HEADS*FOUT)     // 256
#define ROWS  (BATCH*NTOK)     // 4096

// ---------------------------------------------------------------------------
// Workspace layout (float offsets). partial now has its OWN region (the old
// V1 alias would race inside the fused scatter+scan kernel).
// ---------------------------------------------------------------------------
static const size_t OFF_E1   = 1048576;                 // e1  [16][2048]
static const size_t OFF_E2   = OFF_E1 + 32768;          // e2  [16][2048]
static const size_t OFF_SKEY = OFF_E2 + 32768;          // skey[16][2048]
static const size_t OFF_S1   = OFF_SKEY + 32768;        // S1  [16][2049]
static const size_t OFF_P2   = OFF_S1 + 32784;          // P2  [16][2049]
static const size_t OFF_V1   = OFF_P2 + 32784;          // V1  [16][2049][32]
static const size_t OFF_P2V  = OFF_V1 + 16u*2049u*32u;  // P2V [16][2049][32]
static const size_t OFF_PART = OFF_P2V + 16u*2049u*32u; // partial[8][16][2048] int
// total ~14.7 MB << ws_size (~268 MB per fill counters)

#define FMA4(ACC, AV, BV) \
    ACC.x += (AV) * (BV).x; ACC.y += (AV) * (BV).y; \
    ACC.z += (AV) * (BV).z; ACC.w += (AV) * (BV).w;

// ---------------------------------------------------------------------------
// K1: Wh = h @ W (4096x256 @ 256x256 fp32) + fused e1/e2 epilogue.
// 64x64 tile, BK=64, block 256 (16 tc x 16 tr), thread = 4 rows x 4 cols.
// A staged ROW-MAJOR (conflict-free f4 writes, same pattern as B); the A
// fragment is 4x ds_read_b128 along k (one per row; 16 tc lanes broadcast).
// Per kq-group: 8 b128 (~96 cyc) vs 64 FMA (~128 cyc) -> FMA-bound.
// ---------------------------------------------------------------------------
__global__ __launch_bounds__(256) void k_gemm(const float* __restrict__ h,
                                              const float* __restrict__ W,
                                              const float* __restrict__ a,
                                              float* __restrict__ Wh,
                                              float* __restrict__ e1,
                                              float* __restrict__ e2) {
    __shared__ float As[64 * 68];   // [row][k], row stride 68
    __shared__ float Bs[64 * 68];   // [k][col], k stride 68
    __shared__ float av[64];
    const int tid  = threadIdx.x;
    const int row0 = blockIdx.x * 64;
    const int col0 = blockIdx.y * 64;
    const int tc = tid & 15;        // col group (float4)
    const int tr = tid >> 4;        // row group (4 rows)
    const int r0 = tr * 4;
    const int c0 = tc * 4;
    if (tid < 64) av[tid] = a[tid];

    const float4* h4 = (const float4*)h;   // [4096][64]
    const float4* W4 = (const float4*)W;   // [256][64]

    float4 acc[4];
    #pragma unroll
    for (int i = 0; i < 4; ++i) acc[i] = make_float4(0.f,0.f,0.f,0.f);

    for (int kc = 0; kc < FIN; kc += 64) {
        // stage A: 64 rows x 16 f4, contiguous f4 writes (conflict-free)
        #pragma unroll
        for (int q = 0; q < 4; ++q) {
            int idx = q * 256 + tid;
            int r  = idx >> 4;
            int kq = idx & 15;
            *(float4*)&As[r * 68 + kq * 4] =
                h4[(size_t)(row0 + r) * 64 + (kc >> 2) + kq];
        }
        // stage B: 64 k x 16 f4, contiguous f4 writes (conflict-free)
        #pragma unroll
        for (int q = 0; q < 4; ++q) {
            int idx = q * 256 + tid;
            int kr = idx >> 4;
            int cf = idx & 15;
            *(float4*)&Bs[kr * 68 + cf * 4] =
                W4[(size_t)(kc + kr) * 64 + (col0 >> 2) + cf];
        }
        __syncthreads();

        #pragma unroll 4
        for (int kq = 0; kq < 16; ++kq) {
            float4 a0 = *(const float4*)&As[(r0 + 0) * 68 + kq * 4];
            float4 a1 = *(const float4*)&As[(r0 + 1) * 68 + kq * 4];
            float4 a2 = *(const float4*)&As[(r0 + 2) * 68 + kq * 4];
            float4 a3 = *(const float4*)&As[(r0 + 3) * 68 + kq * 4];
            float4 b0 = *(const float4*)&Bs[(kq * 4 + 0) * 68 + c0];
            float4 b1 = *(const float4*)&Bs[(kq * 4 + 1) * 68 + c0];
            float4 b2 = *(const float4*)&Bs[(kq * 4 + 2) * 68 + c0];
            float4 b3 = *(const float4*)&Bs[(kq * 4 + 3) * 68 + c0];
            FMA4(acc[0], a0.x, b0) FMA4(acc[0], a0.y, b1) FMA4(acc[0], a0.z, b2) FMA4(acc[0], a0.w, b3)
            FMA4(acc[1], a1.x, b0) FMA4(acc[1], a1.y, b1) FMA4(acc[1], a1.z, b2) FMA4(acc[1], a1.w, b3)
            FMA4(acc[2], a2.x, b0) FMA4(acc[2], a2.y, b1) FMA4(acc[2], a2.z, b2) FMA4(acc[2], a2.w, b3)
            FMA4(acc[3], a3.x, b0) FMA4(acc[3], a3.y, b1) FMA4(acc[3], a3.z, b2) FMA4(acc[3], a3.w, b3)
        }
        __syncthreads();
    }

    // store Wh
    #pragma unroll
    for (int i = 0; i < 4; ++i)
        *(float4*)(Wh + (size_t)(row0 + r0 + i) * NCOL + col0 + c0) = acc[i];

    // fused e1/e2: f-index within head = (tc*4) & 31
    const int f0 = c0 & 31;
    float s1[4], s2[4];
    #pragma unroll
    for (int i = 0; i < 4; ++i) {
        s1[i] = acc[i].x * av[f0+0] + acc[i].y * av[f0+1] + acc[i].z * av[f0+2] + acc[i].w * av[f0+3];
        s2[i] = acc[i].x * av[32+f0+0] + acc[i].y * av[32+f0+1] + acc[i].z * av[32+f0+2] + acc[i].w * av[32+f0+3];
    }
    #pragma unroll
    for (int m = 1; m < 8; m <<= 1) {
        #pragma unroll
        for (int i = 0; i < 4; ++i) {
            s1[i] += __shfl_xor(s1[i], m, 64);
            s2[i] += __shfl_xor(s2[i], m, 64);
        }
    }
    if ((tc & 7) == 0) {
        const int hh = (col0 >> 5) + (tc >> 3);   // head 0..7
        #pragma unroll
        for (int i = 0; i < 4; ++i) {
            int grow = row0 + r0 + i;
            int b = grow >> 11;
            int n = grow & (NTOK - 1);
            e1[(b * HEADS + hh) * NTOK + n] = s1[i];
            e2[(b * HEADS + hh) * NTOK + n] = s2[i];
        }
    }
}

// ---------------------------------------------------------------------------
// K2: partial descending ranks. grid (16 bh, 8 jtile, 8 ktile), block 256.
// ---------------------------------------------------------------------------
__global__ __launch_bounds__(256) void k_rank8(const float* __restrict__ e2g,
                                               int* __restrict__ partial) {
    __shared__ float ch[256];
    const int tid = threadIdx.x;
    const int bh  = blockIdx.x;
    const int jt  = blockIdx.y;
    const int kt  = blockIdx.z;
    ch[tid] = e2g[bh * NTOK + kt * 256 + tid];
    __syncthreads();

    const int j    = jt * 256 + tid;
    const float my = e2g[bh * NTOK + j];
    const int base0 = kt * 256;
    int rank = 0;
    const float4* c4 = (const float4*)ch;
    #pragma unroll 8
    for (int q = 0; q < 64; ++q) {
        float4 v = c4[q];
        int bb = base0 + q * 4;
        rank += (v.x > my) || ((v.x == my) && (bb + 0 < j));
        rank += (v.y > my) || ((v.y == my) && (bb + 1 < j));
        rank += (v.z > my) || ((v.z == my) && (bb + 2 < j));
        rank += (v.w > my) || ((v.w == my) && (bb + 3 < j));
    }
    partial[(kt * BH + bh) * NTOK + j] = rank;
}

// ---------------------------------------------------------------------------
// K3: fused scatter + dual-scale scan. grid (9 fg, 16 bh), block 1024.
// Phase 1: each block re-derives ranks (sum 8 partials, coalesced) and
//          scatters (key, idx) into LDS. fg==8 block also writes skey.
// Phase 2: thread owns sorted positions j=2t,2t+1; ONE Wh gather feeds both
//          exp(key) and exp(0.01*key) scans (wave shfl + 16-wave combine).
// fg<8: float4 scans -> V1, P2V. fg==8: scalar scans -> S1, P2.
// Exclusive form: dst[k]=incl[k-1], dst[0]=0, dst[2048]=total.
// ---------------------------------------------------------------------------
__global__ __launch_bounds__(1024) void k_scan(const float* __restrict__ e2g,
                                               const int* __restrict__ partial,
                                               const float* __restrict__ Wh,
                                               float* __restrict__ skey,
                                               float* __restrict__ V1,
                                               float* __restrict__ P2V,
                                               float* __restrict__ S1,
                                               float* __restrict__ P2) {
    __shared__ float keyS[NTOK];
    __shared__ int   idxS[NTOK];
    __shared__ float4 wtot1[16], wtot2[16];
    __shared__ float4 woff1[16], woff2[16];
    const int t    = threadIdx.x;
    const int lane = t & 63;
    const int wv   = t >> 6;
    const int fg   = blockIdx.x;   // 0..8
    const int bh   = blockIdx.y;
    const int b    = bh >> 3;
    const int hh   = bh & 7;

    // ---- phase 1: rank-sum + LDS scatter (coalesced global reads) ----
    #pragma unroll
    for (int q = 0; q < 2; ++q) {
        int j = q * 1024 + t;
        int r = 0;
        #pragma unroll
        for (int kt = 0; kt < 8; ++kt)
            r += partial[(kt * BH + bh) * NTOK + j];
        keyS[r] = e2g[bh * NTOK + j];
        idxS[r] = j;
    }
    __syncthreads();
    if (fg == 8) {
        #pragma unroll
        for (int q = 0; q < 2; ++q) {
            int j = q * 1024 + t;
            skey[bh * NTOK + j] = keyS[j];
        }
    }

    // ---- phase 2: dual-scale scan over sorted order ----
    const int j0 = 2 * t;
    float2 kk = *(const float2*)&keyS[j0];      // b64, conflict-free
    int2   sj = *(const int2*)&idxS[j0];
    float w10 = expf(kk.x), w11 = expf(kk.y);
    float w20 = expf(0.01f * kk.x), w21 = expf(0.01f * kk.y);

    float4 u0, u1, v0, v1;   // scale1 pair, scale2 pair
    if (fg < 8) {
        float4 g0 = *(const float4*)(Wh + (size_t)(b * NTOK + sj.x) * NCOL + hh * FOUT + fg * 4);
        float4 g1 = *(const float4*)(Wh + (size_t)(b * NTOK + sj.y) * NCOL + hh * FOUT + fg * 4);
        u0 = make_float4(w10*g0.x, w10*g0.y, w10*g0.z, w10*g0.w);
        u1 = make_float4(w11*g1.x, w11*g1.y, w11*g1.z, w11*g1.w);
        v0 = make_float4(w20*g0.x, w20*g0.y, w20*g0.z, w20*g0.w);
        v1 = make_float4(w21*g1.x, w21*g1.y, w21*g1.z, w21*g1.w);
    } else {
        u0 = make_float4(w10, 0.f, 0.f, 0.f);
        u1 = make_float4(w11, 0.f, 0.f, 0.f);
        v0 = make_float4(w20, 0.f, 0.f, 0.f);
        v1 = make_float4(w21, 0.f, 0.f, 0.f);
    }

    float4 s1 = make_float4(u0.x+u1.x, u0.y+u1.y, u0.z+u1.z, u0.w+u1.w);
    float4 s2 = make_float4(v0.x+v1.x, v0.y+v1.y, v0.z+v1.z, v0.w+v1.w);
    float4 p1 = s1, p2 = s2;   // pair sums (for exclusive-within-wave)
    #pragma unroll
    for (int d = 1; d < 64; d <<= 1) {
        float ax = __shfl_up(s1.x, (unsigned)d, 64);
        float ay = __shfl_up(s1.y, (unsigned)d, 64);
        float az = __shfl_up(s1.z, (unsigned)d, 64);
        float aw = __shfl_up(s1.w, (unsigned)d, 64);
        float bx = __shfl_up(s2.x, (unsigned)d, 64);
        float by = __shfl_up(s2.y, (unsigned)d, 64);
        float bz = __shfl_up(s2.z, (unsigned)d, 64);
        float bw = __shfl_up(s2.w, (unsigned)d, 64);
        if (lane >= d) {
            s1.x += ax; s1.y += ay; s1.z += az; s1.w += aw;
            s2.x += bx; s2.y += by; s2.z += bz; s2.w += bw;
        }
    }
    float4 ex1 = make_float4(s1.x-p1.x, s1.y-p1.y, s1.z-p1.z, s1.w-p1.w);
    float4 ex2 = make_float4(s2.x-p2.x, s2.y-p2.y, s2.z-p2.z, s2.w-p2.w);
    if (lane == 63) { wtot1[wv] = s1; wtot2[wv] = s2; }
    __syncthreads();
    if (t < 16) {
        float4 a1 = wtot1[t], a2 = wtot2[t];
        float4 i1 = a1, i2 = a2;
        #pragma unroll
        for (int d = 1; d < 16; d <<= 1) {
            float ax = __shfl_up(i1.x, (unsigned)d, 16);
            float ay = __shfl_up(i1.y, (unsigned)d, 16);
            float az = __shfl_up(i1.z, (unsigned)d, 16);
            float aw = __shfl_up(i1.w, (unsigned)d, 16);
            float bx = __shfl_up(i2.x, (unsigned)d, 16);
            float by = __shfl_up(i2.y, (unsigned)d, 16);
            float bz = __shfl_up(i2.z, (unsigned)d, 16);
            float bw = __shfl_up(i2.w, (unsigned)d, 16);
            if ((t & 15) >= d) {
                i1.x += ax; i1.y += ay; i1.z += az; i1.w += aw;
                i2.x += bx; i2.y += by; i2.z += bz; i2.w += bw;
            }
        }
        woff1[t] = make_float4(i1.x-a1.x, i1.y-a1.y, i1.z-a1.z, i1.w-a1.w);
        woff2[t] = make_float4(i2.x-a2.x, i2.y-a2.y, i2.z-a2.z, i2.w-a2.w);
    }
    __syncthreads();

    float4 b1 = woff1[wv], b2 = woff2[wv];
    float4 i10 = make_float4(b1.x+ex1.x+u0.x, b1.y+ex1.y+u0.y, b1.z+ex1.z+u0.z, b1.w+ex1.w+u0.w);
    float4 i11 = make_float4(i10.x+u1.x, i10.y+u1.y, i10.z+u1.z, i10.w+u1.w);
    float4 i20 = make_float4(b2.x+ex2.x+v0.x, b2.y+ex2.y+v0.y, b2.z+ex2.z+v0.z, b2.w+ex2.w+v0.w);
    float4 i21 = make_float4(i20.x+v1.x, i20.y+v1.y, i20.z+v1.z, i20.w+v1.w);

    if (fg < 8) {
        *(float4*)(V1  + ((size_t)bh * 2049 + (j0 + 1)) * 32 + fg * 4) = i10;
        *(float4*)(V1  + ((size_t)bh * 2049 + (j0 + 2)) * 32 + fg * 4) = i11;
        *(float4*)(P2V + ((size_t)bh * 2049 + (j0 + 1)) * 32 + fg * 4) = i20;
        *(float4*)(P2V + ((size_t)bh * 2049 + (j0 + 2)) * 32 + fg * 4) = i21;
        if (t == 0) {
            float4 z4 = make_float4(0.f,0.f,0.f,0.f);
            *(float4*)(V1  + ((size_t)bh * 2049) * 32 + fg * 4) = z4;
            *(float4*)(P2V + ((size_t)bh * 2049) * 32 + fg * 4) = z4;
        }
    } else {
        S1[bh * 2049 + j0 + 1] = i10.x;
        S1[bh * 2049 + j0 + 2] = i11.x;
        P2[bh * 2049 + j0 + 1] = i20.x;
        P2[bh * 2049 + j0 + 2] = i21.x;
        if (t == 0) { S1[bh * 2049] = 0.f; P2[bh * 2049] = 0.f; }
    }
}

// ---------------------------------------------------------------------------
// K4: per (b,h,i): binary-search k_i, combine prefix sums, write output.
// grid (64 itile, 16 bh), block 256 = 32 i x 8 fg
// ---------------------------------------------------------------------------
__global__ __launch_bounds__(256) void k_out(const float* __restrict__ skey,
                                             const float* __restrict__ e1g,
                                             const float* __restrict__ S1,
                                             const float* __restrict__ P2,
                                             const float* __restrict__ V1,
                                             const float* __restrict__ P2V,
                                             float* __restrict__ out) {
    __shared__ float keys[NTOK];
    const int tid = threadIdx.x;
    const int it  = blockIdx.x;
    const int bh  = blockIdx.y;
    const int b   = bh >> 3;
    const int hh  = bh & 7;
    #pragma unroll
    for (int q = 0; q < 8; ++q)
        keys[q * 256 + tid] = skey[bh * NTOK + q * 256 + tid];
    __syncthreads();

    const int i  = it * 32 + (tid >> 3);
    const int fg = tid & 7;
    const float e1v = e1g[bh * NTOK + i];
    const float th  = -e1v;
    int lo = 0, hi = NTOK;
    while (lo < hi) {
        int mid = (lo + hi) >> 1;
        if (keys[mid] > th) lo = mid + 1; else hi = mid;
    }
    const int k = lo;
    const float A = expf(e1v);
    const float C = expf(0.01f * e1v);
    const float s1  = S1[bh * 2049 + k];
    const float p2k = P2[bh * 2049 + k];
    const float p2t = P2[bh * 2049 + 2048];
    const float l   = A * s1 + C * (p2t - p2k);
    const float inv = 1.0f / l;
    float4 v1   = *(const float4*)(V1  + ((size_t)bh * 2049 + k)    * 32 + fg * 4);
    float4 p2v  = *(const float4*)(P2V + ((size_t)bh * 2049 + k)    * 32 + fg * 4);
    float4 p2vt = *(const float4*)(P2V + ((size_t)bh * 2049 + 2048) * 32 + fg * 4);
    float4 o;
    o.x = (A * v1.x + C * (p2vt.x - p2v.x)) * inv;
    o.y = (A * v1.y + C * (p2vt.y - p2v.y)) * inv;
    o.z = (A * v1.z + C * (p2vt.z - p2v.z)) * inv;
    o.w = (A * v1.w + C * (p2vt.w - p2v.w)) * inv;
    *(float4*)(out + (size_t)(b * NTOK + i) * NCOL + hh * FOUT + fg * 4) = o;
}

// ---------------------------------------------------------------------------
extern "C" void kernel_launch(void* const* d_in, const int* in_sizes, int n_in,
                              void* d_out, int out_size, void* d_ws, size_t ws_size,
                              hipStream_t stream) {
    const float* h = (const float*)d_in[0];
    // d_in[1] = adj — unused by the reference computation
    const float* W = (const float*)d_in[2];
    const float* a = (const float*)d_in[3];
    float* out = (float*)d_out;
    float* ws  = (float*)d_ws;

    float* Wh   = ws;
    float* e1   = ws + OFF_E1;
    float* e2   = ws + OFF_E2;
    float* skey = ws + OFF_SKEY;
    float* S1   = ws + OFF_S1;
    float* P2   = ws + OFF_P2;
    float* V1   = ws + OFF_V1;
    float* P2V  = ws + OFF_P2V;
    int*   part = (int*)(ws + OFF_PART);

    k_gemm <<<dim3(ROWS / 64, NCOL / 64), 256, 0, stream>>>(h, W, a, Wh, e1, e2);
    k_rank8<<<dim3(BH, 8, 8),             256, 0, stream>>>(e2, part);
    k_scan <<<dim3(9, BH),               1024, 0, stream>>>(e2, part, Wh, skey, V1, P2V, S1, P2);
    k_out  <<<dim3(NTOK / 32, BH),        256, 0, stream>>>(skey, e1, S1, P2, V1, P2V, out);
}